// Round 14
// baseline (26.811 us; speedup 1.0000x reference)
//
#include <hip/hip_runtime.h>
#include <hip/hip_bf16.h>

typedef __attribute__((ext_vector_type(8))) short bf16x8;
typedef __attribute__((ext_vector_type(4))) float f32x4;

__device__ __forceinline__ unsigned short f2bf(float f) {
    unsigned u = __builtin_bit_cast(unsigned, f);
    unsigned rnd = 0x7FFFu + ((u >> 16) & 1u);
    return (unsigned short)((u + rnd) >> 16);
}

// raw barrier: lgkmcnt drain (LDS writes visible) WITHOUT vmcnt drain, so
// in-flight global prefetch loads survive the barrier (R9/R12-verified).
__device__ __forceinline__ void wg_barrier() {
    asm volatile("s_waitcnt lgkmcnt(0)" ::: "memory");
    __builtin_amdgcn_sched_barrier(0);
    __builtin_amdgcn_s_barrier();
    __builtin_amdgcn_sched_barrier(0);
}

// ---------------------------------------------------------------------------
// Setup: simulate the circuit on the 256 basis vectors -> U (256x256),
// packed as bf16 fragments (same map for A- or B-operand; R8-verified):
//   element (n,k): u=n>>4, t=k>>5, lane=((k>>3)&3)*16+(n&15), j=k&7
//   Bp[((u*8+t)*64 + lane)*8 + j]
// ---------------------------------------------------------------------------
__global__ __launch_bounds__(256) void qnn_setup(const float* __restrict__ wts,
                                                 unsigned short* __restrict__ Bp) {
    __shared__ float cs[56], sn[56];
    int tid = threadIdx.x;
    if (tid < 56) {
        float th = 0.5f * wts[tid];
        cs[tid] = cosf(th);
        sn[tid] = sinf(th);
    }
    __syncthreads();

    int l = tid & 63;
    int k = blockIdx.x * 4 + (tid >> 6);   // column 0..255
    int a0 = l << 2;

    float v0 = (float)(a0 + 0 == k);
    float v1 = (float)(a0 + 1 == k);
    float v2 = (float)(a0 + 2 == k);
    float v3 = (float)(a0 + 3 == k);

#pragma unroll
    for (int L = 0; L < 7; ++L) {
#pragma unroll
        for (int q = 0; q <= 5; ++q) {     // RY wires 0..5 (lane bits)
            int m = 5 - q;
            float c = cs[L * 8 + q], s = sn[L * 8 + q];
            float ss = ((l >> m) & 1) ? s : -s;
            float p0 = __shfl_xor(v0, 1 << m);
            float p1 = __shfl_xor(v1, 1 << m);
            float p2 = __shfl_xor(v2, 1 << m);
            float p3 = __shfl_xor(v3, 1 << m);
            v0 = fmaf(ss, p0, c * v0);
            v1 = fmaf(ss, p1, c * v1);
            v2 = fmaf(ss, p2, c * v2);
            v3 = fmaf(ss, p3, c * v3);
        }
        {   // RY wire 6 (reg bit 1)
            float c = cs[L * 8 + 6], s = sn[L * 8 + 6];
            float n0 = fmaf(-s, v2, c * v0), n2 = fmaf(s, v0, c * v2);
            float n1 = fmaf(-s, v3, c * v1), n3 = fmaf(s, v1, c * v3);
            v0 = n0; v1 = n1; v2 = n2; v3 = n3;
        }
        {   // RY wire 7 (reg bit 0)
            float c = cs[L * 8 + 7], s = sn[L * 8 + 7];
            float n0 = fmaf(-s, v1, c * v0), n1 = fmaf(s, v0, c * v1);
            float n2 = fmaf(-s, v3, c * v2), n3 = fmaf(s, v2, c * v3);
            v0 = n0; v1 = n1; v2 = n2; v3 = n3;
        }
        {   // CNOTs q=0..4 (both bits in lane index): composed lane permute
            int src = l;
#pragma unroll
            for (int q = 4; q >= 0; --q)
                src = src ^ (((src >> (5 - q)) & 1) << (4 - q));
            v0 = __shfl(v0, src);
            v1 = __shfl(v1, src);
            v2 = __shfl(v2, src);
            v3 = __shfl(v3, src);
        }
        {   // CNOT q=5: ctl = lane bit0, tgt = reg bit1
            bool cc = (l & 1);
            float n0 = cc ? v2 : v0, n2 = cc ? v0 : v2;
            float n1 = cc ? v3 : v1, n3 = cc ? v1 : v3;
            v0 = n0; v1 = n1; v2 = n2; v3 = n3;
        }
        {   // CNOT q=6: swap v2,v3
            float t = v2; v2 = v3; v3 = t;
        }
    }

    int t = k >> 5, j = k & 7, lk = (k >> 3) & 3;
#pragma unroll
    for (int r = 0; r < 4; ++r) {
        int n = a0 + r;
        int u = n >> 4;
        int ls = lk * 16 + (n & 15);
        float val = (r == 0) ? v0 : (r == 1) ? v1 : (r == 2) ? v2 : v3;
        Bp[(((u * 8 + t) * 64) + ls) * 8 + j] = f2bf(val);
    }
}

// convert one thread's 16 floats (4 float4) of a 32-row tile, store swizzled.
// No norm path (orthogonality, R13-verified).
__device__ __forceinline__ void cvt_store(const float4* pf,
                                          unsigned short (*Xp)[256],
                                          int sr, int qt) {
#pragma unroll
    for (int h2 = 0; h2 < 2; ++h2) {
        float4 a = pf[2 * h2], b = pf[2 * h2 + 1];
        bf16x8 h;
        h[0] = (short)f2bf(a.x); h[1] = (short)f2bf(a.y);
        h[2] = (short)f2bf(a.z); h[3] = (short)f2bf(a.w);
        h[4] = (short)f2bf(b.x); h[5] = (short)f2bf(b.y);
        h[6] = (short)f2bf(b.z); h[7] = (short)f2bf(b.w);
        int chunk = qt * 2 + h2;
        *(bf16x8*)&Xp[sr][(chunk ^ (sr & 7)) * 8] = h;   // bijective XOR swizzle
    }
}

// ---------------------------------------------------------------------------
// Main (R14): R13's verified skeleton with 32-sample tiles (4 phases, halved
// barrier count, 64B/thread HBM in flight = 3x the BW*latency product) and
// s_setprio around the MFMA cluster (T5; 2 interleaved blocks/CU = role
// diversity). 512 blocks x 512 thr x 128 samples, 2 blocks/CU.
// ---------------------------------------------------------------------------
__global__ __launch_bounds__(512, 4) void qnn_main(
    const float* __restrict__ x, const unsigned short* __restrict__ Bp,
    const float* __restrict__ W1, const float* __restrict__ b1,
    const float* __restrict__ W2, const float* __restrict__ b2,
    float* __restrict__ out) {
    __shared__ __align__(16) unsigned short Xs[2][32][256];   // 32 KB
    __shared__ float Qpart[8][128];                           // 4 KB

    int tid = threadIdx.x;
    int l = tid & 63, w = tid >> 6;        // wave 0..7
    int sr = tid >> 4, qt = tid & 15;      // staging: row 0..31, 16-float chunk
    size_t base = (size_t)blockIdx.x * 128 * 256;
    const float* xst = x + base + (size_t)sr * 256 + qt * 16;

    // ---- U fragments (u-blocks 2w, 2w+1), loaded once ----
    const unsigned short* up = Bp + (size_t)(2 * w) * 4096 + l * 8;
    bf16x8 uf0[8], uf1[8];
#pragma unroll
    for (int t = 0; t < 8; ++t) {
        uf0[t] = *(const bf16x8*)(up + t * 512);
        uf1[t] = *(const bf16x8*)(up + 4096 + t * 512);
    }

    // ---- prologue: tiles 0,1 prefetched (4 float4 each); tile 0 -> LDS ----
    float4 pf[2][4];
#pragma unroll
    for (int i = 0; i < 4; ++i) pf[0][i] = *(const float4*)(xst + 4 * i);
#pragma unroll
    for (int i = 0; i < 4; ++i) pf[1][i] = *(const float4*)(xst + 8192 + 4 * i);
    cvt_store(pf[0], Xs[0], sr, qt);
    wg_barrier();

    int row = l & 15, kg = l >> 4;

    // ---- 4-tile pipeline: prefetch(t+2) -> compute(t) -> cvt_store(t+1) ----
#pragma unroll
    for (int t = 0; t < 4; ++t) {
        if (t + 2 < 4) {
#pragma unroll
            for (int i = 0; i < 4; ++i)
                pf[t & 1][i] = *(const float4*)(xst + (size_t)(t + 2) * 8192 + 4 * i);
        }
        // compute tile t: 2 taus x (8 ks x 2 builtin MFMAs)
        __builtin_amdgcn_s_setprio(1);
#pragma unroll
        for (int tau = 0; tau < 2; ++tau) {
            const unsigned short* rp = &Xs[t & 1][tau * 16 + row][0];
            int rsw = (tau * 16 + row) & 7;
            f32x4 a0 = {0.f, 0.f, 0.f, 0.f}, a1 = {0.f, 0.f, 0.f, 0.f};
#pragma unroll
            for (int ks = 0; ks < 8; ++ks) {
                bf16x8 xf = *(const bf16x8*)(rp + (((ks << 2) | kg) ^ rsw) * 8);
                a0 = __builtin_amdgcn_mfma_f32_16x16x32_bf16(uf0[ks], xf, a0, 0, 0, 0);
                a1 = __builtin_amdgcn_mfma_f32_16x16x32_bf16(uf1[ks], xf, a1, 0, 0, 0);
            }
            float q = 0.f;
#pragma unroll
            for (int j = 0; j < 4; ++j)
                q = fmaf(a0[j], a0[j], fmaf(a1[j], a1[j], q));
            q += __shfl_xor(q, 16);        // reduce the 4 n-row groups
            q += __shfl_xor(q, 32);
            if (l < 16) Qpart[w][t * 32 + tau * 16 + l] = q;
        }
        __builtin_amdgcn_s_setprio(0);
        if (t + 1 < 4)
            cvt_store(pf[(t + 1) & 1], Xs[(t + 1) & 1], sr, qt);
        wg_barrier();
    }

    // ---- epilogue: z = (P+ - P-)/(P+ + P-), MLP, sigmoid ----
    if (tid < 128) {
        float pp = Qpart[0][tid] + Qpart[1][tid] + Qpart[2][tid] + Qpart[3][tid];
        float pm = Qpart[4][tid] + Qpart[5][tid] + Qpart[6][tid] + Qpart[7][tid];
        float z = (pp - pm) / (pp + pm);
        float o = b2[0];
#pragma unroll
        for (int jj = 0; jj < 16; ++jj) {
            float h = fmaf(z, W1[jj], b1[jj]);
            h = h > 0.f ? h : 0.f;
            o = fmaf(W2[jj], h, o);
        }
        out[(size_t)blockIdx.x * 128 + tid] = 1.f / (1.f + expf(-o));
    }
}

extern "C" void kernel_launch(void* const* d_in, const int* in_sizes, int n_in,
                              void* d_out, int out_size, void* d_ws, size_t ws_size,
                              hipStream_t stream) {
    const float* x   = (const float*)d_in[0];
    const float* wts = (const float*)d_in[1];
    const float* W1  = (const float*)d_in[2];
    const float* b1  = (const float*)d_in[3];
    const float* W2  = (const float*)d_in[4];
    const float* b2  = (const float*)d_in[5];
    float* out = (float*)d_out;
    unsigned short* Bp = (unsigned short*)d_ws;   // 65536 bf16 = 128 KB

    int B = in_sizes[0] >> 8;        // 65536 samples
    qnn_setup<<<64, 256, 0, stream>>>(wts, Bp);
    qnn_main<<<B / 128, 512, 0, stream>>>(x, Bp, W1, b1, W2, b2, out);
}

// Round 15
// 23.695 us; speedup vs baseline: 1.1315x; 1.1315x over previous
//
#include <hip/hip_runtime.h>
#include <hip/hip_bf16.h>

typedef __attribute__((ext_vector_type(8))) short bf16x8;
typedef __attribute__((ext_vector_type(4))) float f32x4;

__device__ __forceinline__ unsigned short f2bf(float f) {
    unsigned u = __builtin_bit_cast(unsigned, f);
    unsigned rnd = 0x7FFFu + ((u >> 16) & 1u);
    return (unsigned short)((u + rnd) >> 16);
}

// raw barrier: lgkmcnt drain (LDS writes visible) WITHOUT vmcnt drain, so
// in-flight global prefetch loads survive the barrier (R9/R12/R13-verified).
__device__ __forceinline__ void wg_barrier() {
    asm volatile("s_waitcnt lgkmcnt(0)" ::: "memory");
    __builtin_amdgcn_sched_barrier(0);
    __builtin_amdgcn_s_barrier();
    __builtin_amdgcn_sched_barrier(0);
}

// ---------------------------------------------------------------------------
// Setup: simulate the circuit on the 256 basis vectors -> U (256x256),
// packed as bf16 fragments (same map for A- or B-operand; R8-verified):
//   element (n,k): u=n>>4, t=k>>5, lane=((k>>3)&3)*16+(n&15), j=k&7
//   Bp[((u*8+t)*64 + lane)*8 + j]
// ---------------------------------------------------------------------------
__global__ __launch_bounds__(256) void qnn_setup(const float* __restrict__ wts,
                                                 unsigned short* __restrict__ Bp) {
    __shared__ float cs[56], sn[56];
    int tid = threadIdx.x;
    if (tid < 56) {
        float th = 0.5f * wts[tid];
        cs[tid] = cosf(th);
        sn[tid] = sinf(th);
    }
    __syncthreads();

    int l = tid & 63;
    int k = blockIdx.x * 4 + (tid >> 6);   // column 0..255
    int a0 = l << 2;

    float v0 = (float)(a0 + 0 == k);
    float v1 = (float)(a0 + 1 == k);
    float v2 = (float)(a0 + 2 == k);
    float v3 = (float)(a0 + 3 == k);

#pragma unroll
    for (int L = 0; L < 7; ++L) {
#pragma unroll
        for (int q = 0; q <= 5; ++q) {     // RY wires 0..5 (lane bits)
            int m = 5 - q;
            float c = cs[L * 8 + q], s = sn[L * 8 + q];
            float ss = ((l >> m) & 1) ? s : -s;
            float p0 = __shfl_xor(v0, 1 << m);
            float p1 = __shfl_xor(v1, 1 << m);
            float p2 = __shfl_xor(v2, 1 << m);
            float p3 = __shfl_xor(v3, 1 << m);
            v0 = fmaf(ss, p0, c * v0);
            v1 = fmaf(ss, p1, c * v1);
            v2 = fmaf(ss, p2, c * v2);
            v3 = fmaf(ss, p3, c * v3);
        }
        {   // RY wire 6 (reg bit 1)
            float c = cs[L * 8 + 6], s = sn[L * 8 + 6];
            float n0 = fmaf(-s, v2, c * v0), n2 = fmaf(s, v0, c * v2);
            float n1 = fmaf(-s, v3, c * v1), n3 = fmaf(s, v1, c * v3);
            v0 = n0; v1 = n1; v2 = n2; v3 = n3;
        }
        {   // RY wire 7 (reg bit 0)
            float c = cs[L * 8 + 7], s = sn[L * 8 + 7];
            float n0 = fmaf(-s, v1, c * v0), n1 = fmaf(s, v0, c * v1);
            float n2 = fmaf(-s, v3, c * v2), n3 = fmaf(s, v2, c * v3);
            v0 = n0; v1 = n1; v2 = n2; v3 = n3;
        }
        {   // CNOTs q=0..4 (both bits in lane index): composed lane permute
            int src = l;
#pragma unroll
            for (int q = 4; q >= 0; --q)
                src = src ^ (((src >> (5 - q)) & 1) << (4 - q));
            v0 = __shfl(v0, src);
            v1 = __shfl(v1, src);
            v2 = __shfl(v2, src);
            v3 = __shfl(v3, src);
        }
        {   // CNOT q=5: ctl = lane bit0, tgt = reg bit1
            bool cc = (l & 1);
            float n0 = cc ? v2 : v0, n2 = cc ? v0 : v2;
            float n1 = cc ? v3 : v1, n3 = cc ? v1 : v3;
            v0 = n0; v1 = n1; v2 = n2; v3 = n3;
        }
        {   // CNOT q=6: swap v2,v3
            float t = v2; v2 = v3; v3 = t;
        }
    }

    int t = k >> 5, j = k & 7, lk = (k >> 3) & 3;
#pragma unroll
    for (int r = 0; r < 4; ++r) {
        int n = a0 + r;
        int u = n >> 4;
        int ls = lk * 16 + (n & 15);
        float val = (r == 0) ? v0 : (r == 1) ? v1 : (r == 2) ? v2 : v3;
        Bp[(((u * 8 + t) * 64) + ls) * 8 + j] = f2bf(val);
    }
}

// convert one thread's 8 floats of a 16-row tile, store swizzled.
// No norm path: U orthogonal -> denominator = P+ + P- (R13-verified).
__device__ __forceinline__ void cvt_store(const float4& a, const float4& b,
                                          unsigned short (*Xp)[256],
                                          int sr, int qt) {
    bf16x8 h;
    h[0] = (short)f2bf(a.x); h[1] = (short)f2bf(a.y);
    h[2] = (short)f2bf(a.z); h[3] = (short)f2bf(a.w);
    h[4] = (short)f2bf(b.x); h[5] = (short)f2bf(b.y);
    h[6] = (short)f2bf(b.z); h[7] = (short)f2bf(b.w);
    *(bf16x8*)&Xp[sr][(qt ^ (sr & 7)) * 8] = h;       // bijective XOR swizzle
}

// ---------------------------------------------------------------------------
// Main (R15): R13's verified skeleton (16-sample tiles, lgkm-only barriers,
// 2 blocks/CU) with DEPTH-3 prefetch (48B/thread HBM in flight, 1.5x the
// BW*latency product). 512 blocks x 512 thr x 128 samples.
// ---------------------------------------------------------------------------
__global__ __launch_bounds__(512, 4) void qnn_main(
    const float* __restrict__ x, const unsigned short* __restrict__ Bp,
    const float* __restrict__ W1, const float* __restrict__ b1,
    const float* __restrict__ W2, const float* __restrict__ b2,
    float* __restrict__ out) {
    __shared__ __align__(16) unsigned short Xs[2][16][256];   // 16 KB
    __shared__ float Qpart[8][128];                           // 4 KB

    int tid = threadIdx.x;
    int l = tid & 63, w = tid >> 6;        // wave 0..7
    int sr = tid >> 5, qt = tid & 31;      // staging: row 0..15, 8-float chunk
    size_t base = (size_t)blockIdx.x * 128 * 256;
    const float* xst = x + base + (size_t)sr * 256 + qt * 8;

    // ---- U fragments (u-blocks 2w, 2w+1), loaded once ----
    const unsigned short* up = Bp + (size_t)(2 * w) * 4096 + l * 8;
    bf16x8 uf0[8], uf1[8];
#pragma unroll
    for (int t = 0; t < 8; ++t) {
        uf0[t] = *(const bf16x8*)(up + t * 512);
        uf1[t] = *(const bf16x8*)(up + 4096 + t * 512);
    }

    // ---- prologue: tiles 0,1,2 prefetched; tile 0 converted to LDS ----
    float4 pf[3][2];
#pragma unroll
    for (int i = 0; i < 3; ++i) {
        pf[i][0] = *(const float4*)(xst + (size_t)i * 4096);
        pf[i][1] = *(const float4*)(xst + (size_t)i * 4096 + 4);
    }
    cvt_store(pf[0][0], pf[0][1], Xs[0], sr, qt);
    wg_barrier();

    int row = l & 15, kg = l >> 4;

    // ---- 8-tile pipeline: prefetch(t+3) -> compute(t) -> cvt_store(t+1) ----
#pragma unroll
    for (int t = 0; t < 8; ++t) {
        if (t + 3 < 8) {
            pf[t % 3][0] = *(const float4*)(xst + (size_t)(t + 3) * 4096);
            pf[t % 3][1] = *(const float4*)(xst + (size_t)(t + 3) * 4096 + 4);
        }
        {   // compute tile t: 8 ksteps x 2 builtin MFMAs
            const unsigned short* rp = &Xs[t & 1][row][0];
            f32x4 a0 = {0.f, 0.f, 0.f, 0.f}, a1 = {0.f, 0.f, 0.f, 0.f};
#pragma unroll
            for (int ks = 0; ks < 8; ++ks) {
                bf16x8 xf = *(const bf16x8*)(rp + (((ks << 2) | kg) ^ (row & 7)) * 8);
                a0 = __builtin_amdgcn_mfma_f32_16x16x32_bf16(uf0[ks], xf, a0, 0, 0, 0);
                a1 = __builtin_amdgcn_mfma_f32_16x16x32_bf16(uf1[ks], xf, a1, 0, 0, 0);
            }
            float q = 0.f;
#pragma unroll
            for (int j = 0; j < 4; ++j)
                q = fmaf(a0[j], a0[j], fmaf(a1[j], a1[j], q));
            q += __shfl_xor(q, 16);        // reduce the 4 n-row groups
            q += __shfl_xor(q, 32);
            if (l < 16) Qpart[w][t * 16 + l] = q;
        }
        if (t + 1 < 8)
            cvt_store(pf[(t + 1) % 3][0], pf[(t + 1) % 3][1],
                      Xs[(t + 1) & 1], sr, qt);
        wg_barrier();
    }

    // ---- epilogue: z = (P+ - P-)/(P+ + P-), MLP, sigmoid ----
    if (tid < 128) {
        float pp = Qpart[0][tid] + Qpart[1][tid] + Qpart[2][tid] + Qpart[3][tid];
        float pm = Qpart[4][tid] + Qpart[5][tid] + Qpart[6][tid] + Qpart[7][tid];
        float z = (pp - pm) / (pp + pm);
        float o = b2[0];
#pragma unroll
        for (int jj = 0; jj < 16; ++jj) {
            float h = fmaf(z, W1[jj], b1[jj]);
            h = h > 0.f ? h : 0.f;
            o = fmaf(W2[jj], h, o);
        }
        out[(size_t)blockIdx.x * 128 + tid] = 1.f / (1.f + expf(-o));
    }
}

extern "C" void kernel_launch(void* const* d_in, const int* in_sizes, int n_in,
                              void* d_out, int out_size, void* d_ws, size_t ws_size,
                              hipStream_t stream) {
    const float* x   = (const float*)d_in[0];
    const float* wts = (const float*)d_in[1];
    const float* W1  = (const float*)d_in[2];
    const float* b1  = (const float*)d_in[3];
    const float* W2  = (const float*)d_in[4];
    const float* b2  = (const float*)d_in[5];
    float* out = (float*)d_out;
    unsigned short* Bp = (unsigned short*)d_ws;   // 65536 bf16 = 128 KB

    int B = in_sizes[0] >> 8;        // 65536 samples
    qnn_setup<<<64, 256, 0, stream>>>(wts, Bp);
    qnn_main<<<B / 128, 512, 0, stream>>>(x, Bp, W1, b1, W2, b2, out);
}